// Round 4
// baseline (519.308 us; speedup 1.0000x reference)
//
#include <hip/hip_runtime.h>
#include <hip/hip_bf16.h>

// DeepseekV3 MoE calibrate: T=1024 tokens, H=1024, I=512, E=32, top-8, group-4/top-2.
// Round 3 (resubmit; rounds 1-3 all failed with GPUAcquisitionTimeout, no HW feedback):
// bf16-convert pass + MFMA GEMMs (128x128x64 tile, global_load_lds w/ XOR swizzle),
// dense all-expert compute, routing weights folded into act, atomic fp32 combine.

typedef __attribute__((ext_vector_type(8))) short short8v;
typedef __attribute__((ext_vector_type(4))) float f32x4;

#define GLOAD_LDS(gp, lp)                                                      \
  __builtin_amdgcn_global_load_lds(                                            \
      (const __attribute__((address_space(1))) void*)(gp),                     \
      (__attribute__((address_space(3))) void*)(lp), 16, 0, 0)

__device__ __forceinline__ unsigned short f2bf(float f) {
  unsigned int u = __float_as_uint(f);
  u = (u + 0x7fffu + ((u >> 16) & 1u)) >> 16;
  return (unsigned short)u;
}
__device__ __forceinline__ float bf2f(unsigned short b) {
  return __uint_as_float(((unsigned int)b) << 16);
}

// ---------------- fp32 -> bf16 conversion ----------------
__global__ void convert_kernel(const float* __restrict__ src,
                               unsigned short* __restrict__ dst, long n) {
  long i = ((long)blockIdx.x * blockDim.x + threadIdx.x) * 4;
  long stride = (long)gridDim.x * blockDim.x * 4;
  for (; i < n; i += stride) {
    float4 v = *(const float4*)(src + i);
    ushort4 o;
    o.x = f2bf(v.x); o.y = f2bf(v.y); o.z = f2bf(v.z); o.w = f2bf(v.w);
    *(ushort4*)(dst + i) = o;
  }
}

// ---------------- routing (DeepseekV3TopkRouter) ----------------
// One block per token. Produces dense W[t][32]: topk_w * 2.5 at selected, else 0.
__global__ void gate_kernel(const float* __restrict__ x, const float* __restrict__ gw,
                            const float* __restrict__ gb, float* __restrict__ W) {
  int t = blockIdx.x;
  int tid = threadIdx.x;
  __shared__ float partial[256];
  __shared__ float logits[32];
  const float* xr = x + (long)t * 1024;
  int e = tid & 31, c = tid >> 5;  // 8 chunks of 128 per expert
  const float* wr = gw + (long)e * 1024 + c * 128;
  const float* xc = xr + c * 128;
  float s = 0.f;
  for (int h = 0; h < 128; h += 4) {
    float4 xv = *(const float4*)(xc + h);
    float4 wv = *(const float4*)(wr + h);
    s += xv.x * wv.x + xv.y * wv.y + xv.z * wv.z + xv.w * wv.w;
  }
  partial[tid] = s;
  __syncthreads();
  if (tid < 32) {
    float l = 0.f;
    for (int cc = 0; cc < 8; cc++) l += partial[tid + 32 * cc];
    logits[tid] = l;
  }
  __syncthreads();
  if (tid == 0) {
    float scores[32], sc[32];
    for (int i = 0; i < 32; i++) {
      float s1 = 1.f / (1.f + expf(-logits[i]));
      scores[i] = s1;
      sc[i] = s1 + gb[i];
    }
    // group scores = sum of top-2 biased scores per group of 8
    float gsc[4];
    for (int g = 0; g < 4; g++) {
      float m1 = -1e30f, m2 = -1e30f;
      for (int j = 0; j < 8; j++) {
        float v = sc[g * 8 + j];
        if (v > m1) { m2 = m1; m1 = v; }
        else if (v > m2) m2 = v;
      }
      gsc[g] = m1 + m2;
    }
    int g1 = 0;
    for (int g = 1; g < 4; g++) if (gsc[g] > gsc[g1]) g1 = g;
    int g2 = -1;
    for (int g = 0; g < 4; g++) {
      if (g == g1) continue;
      if (g2 < 0 || gsc[g] > gsc[g2]) g2 = g;
    }
    float masked[32];
    for (int i = 0; i < 32; i++) {
      int g = i >> 3;
      masked[i] = (g == g1 || g == g2) ? sc[i] : 0.0f;
    }
    int idx[8]; float tw[8]; float wsum = 0.f;
    for (int k = 0; k < 8; k++) {
      int best = 0; float bv = -1e30f;
      for (int i = 0; i < 32; i++) if (masked[i] > bv) { bv = masked[i]; best = i; }
      idx[k] = best;
      masked[best] = -2e30f;
      tw[k] = scores[best];
      wsum += tw[k];
    }
    float inv = 2.5f / (wsum + 1e-20f);
    float wout[32];
    for (int i = 0; i < 32; i++) wout[i] = 0.f;
    for (int k = 0; k < 8; k++) wout[idx[k]] = tw[k] * inv;
    for (int i = 0; i < 32; i++) W[t * 32 + i] = wout[i];
  }
}

// ---------------- MFMA GEMM core: C[128x128] tile of A[M,K] * B[N,K]^T ----------------
// LDS tiles [128][64] bf16, XOR-swizzled (chunk ^= row&7) via pre-swizzled global source
// (global_load_lds writes linearly: wave-uniform base + lane*16B).
__device__ __forceinline__ void gemm_tile(const unsigned short* __restrict__ Ag,
                                          const unsigned short* __restrict__ Bg,
                                          int ldA, int ldB, int K, int m0, int n0,
                                          unsigned short* As, unsigned short* Bs,
                                          f32x4 acc[4][4]) {
  int tid = threadIdx.x;
  int lane = tid & 63;
  int w = tid >> 6;          // wave 0..3
  int lrow = lane >> 3;      // 0..7 row within stripe
  int lslot = lane & 7;      // 16B slot within row
  int csrc = lslot ^ lrow;   // pre-swizzled source chunk
  int wr = w >> 1, wc = w & 1;
  int lm = lane & 15, lk = lane >> 4;
  for (int k0 = 0; k0 < K; k0 += 64) {
    __syncthreads();
#pragma unroll
    for (int r = 0; r < 4; r++) {
      int stripe = r * 32 + w * 8;
      const unsigned short* gp = Ag + (long)(m0 + stripe + lrow) * ldA + k0 + csrc * 8;
      GLOAD_LDS(gp, As + stripe * 64);
    }
#pragma unroll
    for (int r = 0; r < 4; r++) {
      int stripe = r * 32 + w * 8;
      const unsigned short* gp = Bg + (long)(n0 + stripe + lrow) * ldB + k0 + csrc * 8;
      GLOAD_LDS(gp, Bs + stripe * 64);
    }
    __syncthreads();
#pragma unroll
    for (int ks = 0; ks < 2; ks++) {
      short8v af[4], bv[4];
#pragma unroll
      for (int mi = 0; mi < 4; mi++) {
        int rA = wr * 64 + mi * 16 + lm;
        int cA = ks * 4 + lk;
        af[mi] = *(const short8v*)(As + rA * 64 + ((cA ^ (rA & 7)) * 8));
      }
#pragma unroll
      for (int ni = 0; ni < 4; ni++) {
        int rB = wc * 64 + ni * 16 + lm;
        int cB = ks * 4 + lk;
        bv[ni] = *(const short8v*)(Bs + rB * 64 + ((cB ^ (rB & 7)) * 8));
      }
#pragma unroll
      for (int mi = 0; mi < 4; mi++)
#pragma unroll
        for (int ni = 0; ni < 4; ni++)
          acc[mi][ni] = __builtin_amdgcn_mfma_f32_16x16x32_bf16(af[mi], bv[ni],
                                                                acc[mi][ni], 0, 0, 0);
    }
  }
}

// C stored bf16. grid: (N/128, M/128, E). B += z*strideBe, C += z*strideCe.
__global__ __launch_bounds__(256) void gemm_store_kernel(
    const unsigned short* __restrict__ A, const unsigned short* __restrict__ B,
    unsigned short* __restrict__ C, int ldA, int ldB, int ldC, int K,
    long strideBe, long strideCe) {
  __shared__ unsigned short As[128 * 64];
  __shared__ unsigned short Bs[128 * 64];
  int n0 = blockIdx.x * 128, m0 = blockIdx.y * 128;
  long e = blockIdx.z;
  f32x4 zero = {0.f, 0.f, 0.f, 0.f};
  f32x4 acc[4][4];
#pragma unroll
  for (int mi = 0; mi < 4; mi++)
#pragma unroll
    for (int ni = 0; ni < 4; ni++) acc[mi][ni] = zero;
  gemm_tile(A, B + e * strideBe, ldA, ldB, K, m0, n0, As, Bs, acc);
  unsigned short* Ce = C + e * strideCe;
  int lane = threadIdx.x & 63, w = threadIdx.x >> 6;
  int wr = w >> 1, wc = w & 1;
  int lm = lane & 15, lk = lane >> 4;
#pragma unroll
  for (int mi = 0; mi < 4; mi++) {
#pragma unroll
    for (int ni = 0; ni < 4; ni++) {
      f32x4 v = acc[mi][ni];
      int col = n0 + wc * 64 + ni * 16 + lm;
      int rbase = m0 + wr * 64 + mi * 16 + lk * 4;
#pragma unroll
      for (int j = 0; j < 4; j++)
        Ce[(long)(rbase + j) * ldC + col] = f2bf(v[j]);
    }
  }
}

// Down projection: C[T,1024] fp32 += sum_e actW[e] * down[e]^T, atomic accumulate.
// grid: (H/128, T/128, n_groups); each block loops epg experts.
__global__ __launch_bounds__(256) void gemm_down_kernel(
    const unsigned short* __restrict__ A, const unsigned short* __restrict__ B,
    float* __restrict__ C, int ldA, int ldB, int K, int epg,
    long strideAe, long strideBe) {
  __shared__ unsigned short As[128 * 64];
  __shared__ unsigned short Bs[128 * 64];
  int n0 = blockIdx.x * 128, m0 = blockIdx.y * 128;
  long ebase = (long)blockIdx.z * epg;
  f32x4 zero = {0.f, 0.f, 0.f, 0.f};
  f32x4 acc[4][4];
#pragma unroll
  for (int mi = 0; mi < 4; mi++)
#pragma unroll
    for (int ni = 0; ni < 4; ni++) acc[mi][ni] = zero;
  for (int ee = 0; ee < epg; ee++) {
    gemm_tile(A + (ebase + ee) * strideAe, B + (ebase + ee) * strideBe,
              ldA, ldB, K, m0, n0, As, Bs, acc);
  }
  int lane = threadIdx.x & 63, w = threadIdx.x >> 6;
  int wr = w >> 1, wc = w & 1;
  int lm = lane & 15, lk = lane >> 4;
#pragma unroll
  for (int mi = 0; mi < 4; mi++) {
#pragma unroll
    for (int ni = 0; ni < 4; ni++) {
      f32x4 v = acc[mi][ni];
      int col = n0 + wc * 64 + ni * 16 + lm;
      int rbase = m0 + wr * 64 + mi * 16 + lk * 4;
#pragma unroll
      for (int j = 0; j < 4; j++)
        atomicAdd(&C[(long)(rbase + j) * 1024 + col], v[j]);
    }
  }
}

// act = silu(g) * u * weight; experts layout [e][t][i], I=512, T=1024.
__global__ void act_kernel(const unsigned short* __restrict__ g,
                           const unsigned short* __restrict__ u,
                           const float* __restrict__ W,
                           unsigned short* __restrict__ out, long n4, int useW) {
  long i = (long)blockIdx.x * blockDim.x + threadIdx.x;
  long stride = (long)gridDim.x * blockDim.x;
  for (; i < n4; i += stride) {
    long base = i * 4;
    float wgt = 1.f;
    if (useW) {
      long ti = base >> 9;             // (e*1024 + t)
      int t = (int)(ti & 1023);
      int e = (int)(ti >> 10);
      wgt = W[t * 32 + e];
    }
    ushort4 gv = *(const ushort4*)(g + base);
    ushort4 uv = *(const ushort4*)(u + base);
    float r0, r1, r2, r3;
    {
      float gf = bf2f(gv.x), uf = bf2f(uv.x);
      r0 = gf / (1.f + expf(-gf)) * uf * wgt;
    }
    {
      float gf = bf2f(gv.y), uf = bf2f(uv.y);
      r1 = gf / (1.f + expf(-gf)) * uf * wgt;
    }
    {
      float gf = bf2f(gv.z), uf = bf2f(uv.z);
      r2 = gf / (1.f + expf(-gf)) * uf * wgt;
    }
    {
      float gf = bf2f(gv.w), uf = bf2f(uv.w);
      r3 = gf / (1.f + expf(-gf)) * uf * wgt;
    }
    ushort4 o;
    o.x = f2bf(r0); o.y = f2bf(r1); o.z = f2bf(r2); o.w = f2bf(r3);
    *(ushort4*)(out + base) = o;
  }
}

extern "C" void kernel_launch(void* const* d_in, const int* in_sizes, int n_in,
                              void* d_out, int out_size, void* d_ws, size_t ws_size,
                              hipStream_t stream) {
  const float* x  = (const float*)d_in[0];   // [1024,1024]
  const float* gw = (const float*)d_in[1];   // [32,1024]
  const float* gb = (const float*)d_in[2];   // [32]
  const float* eg = (const float*)d_in[3];   // [32,512,1024]
  const float* eu = (const float*)d_in[4];   // [32,512,1024]
  const float* ed = (const float*)d_in[5];   // [32,1024,512]
  const float* sg = (const float*)d_in[6];   // [1024,1024]
  const float* su = (const float*)d_in[7];   // [1024,1024]
  const float* sd = (const float*)d_in[8];   // [1024,1024]
  float* out = (float*)d_out;

  char* ws = (char*)d_ws;
  size_t off = 0;
  auto alloc = [&](size_t bytes) {
    off = (off + 255) & ~(size_t)255;
    void* p = ws + off;
    off += bytes;
    return p;
  };
  unsigned short* xb   = (unsigned short*)alloc(1048576L * 2);
  unsigned short* egb  = (unsigned short*)alloc(16777216L * 2);
  unsigned short* eub  = (unsigned short*)alloc(16777216L * 2);
  unsigned short* edb  = (unsigned short*)alloc(16777216L * 2);
  unsigned short* sgb  = (unsigned short*)alloc(1048576L * 2);
  unsigned short* sub  = (unsigned short*)alloc(1048576L * 2);
  unsigned short* sdb  = (unsigned short*)alloc(1048576L * 2);
  float*          Wrt  = (float*)alloc(1024L * 32 * 4);
  unsigned short* gbuf = (unsigned short*)alloc(16777216L * 2);
  unsigned short* ubuf = (unsigned short*)alloc(16777216L * 2);
  unsigned short* gsb  = (unsigned short*)alloc(1048576L * 2);
  unsigned short* usb  = (unsigned short*)alloc(1048576L * 2);

  convert_kernel<<<1024, 256, 0, stream>>>(x, xb, 1048576L);
  convert_kernel<<<4096, 256, 0, stream>>>(eg, egb, 16777216L);
  convert_kernel<<<4096, 256, 0, stream>>>(eu, eub, 16777216L);
  convert_kernel<<<4096, 256, 0, stream>>>(ed, edb, 16777216L);
  convert_kernel<<<1024, 256, 0, stream>>>(sg, sgb, 1048576L);
  convert_kernel<<<1024, 256, 0, stream>>>(su, sub, 1048576L);
  convert_kernel<<<1024, 256, 0, stream>>>(sd, sdb, 1048576L);

  gate_kernel<<<1024, 256, 0, stream>>>(x, gw, gb, Wrt);

  dim3 blk(256);
  // g = x @ expert_gate^T  [32][1024,512];  u likewise
  gemm_store_kernel<<<dim3(4, 8, 32), blk, 0, stream>>>(xb, egb, gbuf, 1024, 1024, 512,
                                                        1024, 524288L, 524288L);
  gemm_store_kernel<<<dim3(4, 8, 32), blk, 0, stream>>>(xb, eub, ubuf, 1024, 1024, 512,
                                                        1024, 524288L, 524288L);
  // shared g/u: [1024,1024]
  gemm_store_kernel<<<dim3(8, 8, 1), blk, 0, stream>>>(xb, sgb, gsb, 1024, 1024, 1024,
                                                       1024, 0L, 0L);
  gemm_store_kernel<<<dim3(8, 8, 1), blk, 0, stream>>>(xb, sub, usb, 1024, 1024, 1024,
                                                       1024, 0L, 0L);

  // act' = silu(g)*u*W  (routing weight folded in; in-place over g)
  act_kernel<<<4096, 256, 0, stream>>>(gbuf, ubuf, Wrt, gbuf, 4194304L, 1);
  act_kernel<<<1024, 256, 0, stream>>>(gsb, usb, nullptr, gsb, 262144L, 0);

  hipMemsetAsync(d_out, 0, (size_t)out_size * 4, stream);

  // out += sum_e act'[e] @ down[e]^T   (8 groups of 4 experts, atomic combine)
  gemm_down_kernel<<<dim3(8, 8, 8), blk, 0, stream>>>(gbuf, edb, out, 512, 512, 512, 4,
                                                      524288L, 524288L);
  // out += shared act @ shared_down^T
  gemm_down_kernel<<<dim3(8, 8, 1), blk, 0, stream>>>(gsb, sdb, out, 1024, 1024, 1024, 1,
                                                      0L, 0L);
}